// Round 3
// baseline (84.013 us; speedup 1.0000x reference)
//
#include <hip/hip_runtime.h>

#define CCH 128
#define SP  4096          // 64*64 spatial positions per (b,c)
#define LSTR 66           // LDS row stride in float2: rows alias banks every 8 rows only
#define TBL_N (9 * SP)

__device__ __forceinline__ float sigmoidf_(float z) {
  return 1.0f / (1.0f + __expf(-z));
}

// One-time gather table: tbl[s*4096+wh] = float2-LDS offset (sw*66+sh) or 0xFFFF.
__global__ __launch_bounds__(256) void k_table(unsigned short* __restrict__ tbl) {
  int i = blockIdx.x * 256 + threadIdx.x;
  if (i >= TBL_N) return;
  int s  = i >> 12, wh = i & (SP - 1);
  int q  = (s << 12) + wh;       // flat index into torch's reinterpreted view
  int wi = q / 576;  int r  = q - wi * 576;
  int hi = r / 9;    int kk = r - hi * 9;
  int di = kk / 3,   dj = kk - di * 3;
  int sw = wi + di - 1, sh = hi + dj - 1;
  tbl[i] = (((unsigned)sw < 64u) & ((unsigned)sh < 64u))
               ? (unsigned short)(sw * LSTR + sh) : (unsigned short)0xFFFFu;
}

// y[b,o,n] = sum_c attn_w[o][c] * x[b,c,n], written into d_out.
// Block 256 thr = 4 waves; wave: 16 o's, 128 n's (2 per thread).
// Weights read as float4 (16 loads per 4 c's) -> 4096 FMA : 768 loads per wave.
__global__ __launch_bounds__(256) void k_conv1x1(
    const float* __restrict__ x, const float* __restrict__ attn_w,
    float* __restrict__ y) {
  int blk   = blockIdx.x;         // B*32*2 = 512
  int b     = blk >> 6;
  int nslab = (blk & 63) >> 1;    // 0..31 -> 128 n each
  int ohalf = blk & 1;
  int lane  = threadIdx.x & 63;
  int o0    = __builtin_amdgcn_readfirstlane(
                  (ohalf << 6) + ((threadIdx.x >> 6) << 4));  // wave-uniform
  int n0    = (nslab << 7) + lane;

  const float* xb = x + ((size_t)b << 19);
  float acc0[16], acc1[16];
#pragma unroll
  for (int j = 0; j < 16; j++) { acc0[j] = 0.0f; acc1[j] = 0.0f; }

  for (int c4 = 0; c4 < CCH / 4; c4++) {
    float4 w4[16];
#pragma unroll
    for (int j = 0; j < 16; j++)
      w4[j] = *(const float4*)&attn_w[((o0 + j) << 7) + (c4 << 2)];
    float xv0[4], xv1[4];
#pragma unroll
    for (int i = 0; i < 4; i++) {
      const float* xc = xb + ((size_t)((c4 << 2) + i) << 12);
      xv0[i] = xc[n0];
      xv1[i] = xc[n0 + 64];
    }
#pragma unroll
    for (int j = 0; j < 16; j++) {
      acc0[j] = fmaf(xv0[0], w4[j].x, acc0[j]);
      acc0[j] = fmaf(xv0[1], w4[j].y, acc0[j]);
      acc0[j] = fmaf(xv0[2], w4[j].z, acc0[j]);
      acc0[j] = fmaf(xv0[3], w4[j].w, acc0[j]);
      acc1[j] = fmaf(xv1[0], w4[j].x, acc1[j]);
      acc1[j] = fmaf(xv1[1], w4[j].y, acc1[j]);
      acc1[j] = fmaf(xv1[2], w4[j].z, acc1[j]);
      acc1[j] = fmaf(xv1[3], w4[j].w, acc1[j]);
    }
  }

  float* yb = y + ((size_t)b << 19) + (nslab << 7) + lane;
#pragma unroll
  for (int j = 0; j < 16; j++) {
    yb[(size_t)(o0 + j) << 12]        = acc0[j];   // coalesced
    yb[((size_t)(o0 + j) << 12) + 64] = acc1[j];
  }
}

// out[b,c,wh] = max_s se[s]*xg * sigmoid(se[s]*yg + attn_b[c]).
// Block = one (b,c) plane; x,y interleaved as float2 in padded LDS;
// gather = one ds_read_b64 per tap; result overwrites the y-plane in d_out.
template <bool TBL>
__global__ __launch_bounds__(256) void k_attnmax(
    const float* __restrict__ x, float* __restrict__ yo,
    const float* __restrict__ se_param, const float* __restrict__ attn_b,
    const unsigned short* __restrict__ tbl) {
  __shared__ __align__(16) float2 lxy[64 * LSTR];
  __shared__ float se9[12];

  int bc = blockIdx.x;            // b*128 + c
  int c  = bc & (CCH - 1);
  const float* xp = x  + ((size_t)bc << 12);
  float*       yp = yo + ((size_t)bc << 12);

  if (threadIdx.x < 9) se9[threadIdx.x] = sigmoidf_(se_param[threadIdx.x]);

  for (int i = threadIdx.x; i < SP / 4; i += 256) {   // 1024 float4 per plane
    float4 vx = ((const float4*)xp)[i];
    float4 vy = ((const float4*)yp)[i];
    float2* dst = &lxy[(i >> 4) * LSTR + ((i & 15) << 2)];
    *(float4*)(dst)     = make_float4(vx.x, vy.x, vx.y, vy.y);  // 16B-aligned
    *(float4*)(dst + 2) = make_float4(vx.z, vy.z, vx.w, vy.w);
  }
  float ab = attn_b[c];
  __syncthreads();

  for (int k = 0; k < 16; k++) {
    int wh = (k << 8) | threadIdx.x;
    float m = -3.4e38f;
#pragma unroll
    for (int s = 0; s < 9; s++) {
      int off; bool valid;
      if (TBL) {
        unsigned short t = tbl[(s << 12) | wh];       // coalesced, L2-hot
        valid = (t != 0xFFFFu);
        off = valid ? (int)t : 0;
      } else {
        int q  = (s << 12) + wh;
        int wi = q / 576;  int r  = q - wi * 576;
        int hi = r / 9;    int kk = r - hi * 9;
        int di = kk / 3,   dj = kk - di * 3;
        int sw = wi + di - 1, sh = hi + dj - 1;
        valid = ((unsigned)sw < 64u) & ((unsigned)sh < 64u);
        off = valid ? sw * LSTR + sh : 0;
      }
      float se = se9[s];
      float2 xy = lxy[off];                           // one ds_read_b64
      float v  = se * xy.x * sigmoidf_(fmaf(se, xy.y, ab));
      v = valid ? v : 0.0f;      // OOB tap contributes weighted=0
      m = fmaxf(m, v);
    }
    yp[wh] = m;                  // overwrite y-plane (y already staged in LDS)
  }
}

extern "C" void kernel_launch(void* const* d_in, const int* in_sizes, int n_in,
                              void* d_out, int out_size, void* d_ws, size_t ws_size,
                              hipStream_t stream) {
  const float* x        = (const float*)d_in[0];
  const float* se_param = (const float*)d_in[1];
  const float* attn_w   = (const float*)d_in[2];
  const float* attn_b   = (const float*)d_in[3];
  float* out = (float*)d_out;

  int B = in_sizes[0] / (CCH * SP);
  unsigned short* tbl = (unsigned short*)d_ws;
  bool use_tbl = ws_size >= (size_t)TBL_N * sizeof(unsigned short);

  if (use_tbl)
    k_table<<<dim3((TBL_N + 255) / 256), dim3(256), 0, stream>>>(tbl);

  k_conv1x1<<<dim3(B * 64), dim3(256), 0, stream>>>(x, attn_w, out);

  if (use_tbl)
    k_attnmax<true><<<dim3(B * CCH), dim3(256), 0, stream>>>(
        x, out, se_param, attn_b, tbl);
  else
    k_attnmax<false><<<dim3(B * CCH), dim3(256), 0, stream>>>(
        x, out, se_param, attn_b, nullptr);
}